// Round 6
// baseline (958.434 us; speedup 1.0000x reference)
//
#include <hip/hip_runtime.h>
#include <hip/hip_bf16.h>
#include <cmath>

#define N_NODES 50000
#define IN_F 64
#define L 128
#define STEPS 3
#define T_TYPES 4
#define E_EDGES 800000
#define NB4 (N_NODES * 4)

typedef __attribute__((ext_vector_type(8))) __bf16 bf16x8_t;
typedef __attribute__((ext_vector_type(4))) float f32x4;

__device__ inline float bf2f(ushort u) {
  union { uint i; float f; } v; v.i = ((uint)u) << 16; return v.f;
}
__device__ inline ushort f2bf(float f) {
  union { float f; uint u; } v; v.f = f;
  uint u = v.u;
  u += 0x7fffu + ((u >> 16) & 1u);  // RNE
  return (ushort)(u >> 16);
}

// ---------------- fp32 tiled matmul for x0 (K=64), writes bf16 ----------------
#define BN 64
#define BO 64
#define BK 16
__global__ __launch_bounds__(256) void matmul_x0(
    const float* __restrict__ A, const float* __restrict__ W,
    const float* __restrict__ bias, ushort* __restrict__ Cb,
    int N, int K, int OUT)
{
  __shared__ float As[BN][BK + 1];
  __shared__ float Ws[BO][BK + 1];
  const int tid = threadIdx.x;
  const int n_base = blockIdx.x * BN;
  const int o_base = blockIdx.y * BO;
  const int tx = tid & 15, ty = tid >> 4;
  const int n0 = ty * 4, o0 = tx * 4;
  const int lr = tid >> 2, lc = (tid & 3) * 4;
  float acc[4][4] = {{0.f, 0.f, 0.f, 0.f}};
  for (int kc = 0; kc < K; kc += BK) {
    int gn = n_base + lr;
    float4 av = make_float4(0.f, 0.f, 0.f, 0.f);
    if (gn < N) av = *(const float4*)(A + (size_t)gn * K + kc + lc);
    As[lr][lc + 0] = av.x; As[lr][lc + 1] = av.y;
    As[lr][lc + 2] = av.z; As[lr][lc + 3] = av.w;
    float4 wv = *(const float4*)(W + (size_t)(o_base + lr) * K + kc + lc);
    Ws[lr][lc + 0] = wv.x; Ws[lr][lc + 1] = wv.y;
    Ws[lr][lc + 2] = wv.z; Ws[lr][lc + 3] = wv.w;
    __syncthreads();
#pragma unroll
    for (int kk = 0; kk < BK; ++kk) {
      float a[4], w[4];
#pragma unroll
      for (int i = 0; i < 4; ++i) a[i] = As[n0 + i][kk];
#pragma unroll
      for (int j = 0; j < 4; ++j) w[j] = Ws[o0 + j][kk];
#pragma unroll
      for (int i = 0; i < 4; ++i)
#pragma unroll
        for (int j = 0; j < 4; ++j) acc[i][j] += a[i] * w[j];
    }
    __syncthreads();
  }
#pragma unroll
  for (int i = 0; i < 4; ++i) {
    int gn = n_base + n0 + i;
    if (gn >= N) continue;
    int o = o_base + o0;
    float v0 = fmaxf(acc[i][0] + bias[o + 0], 0.f);
    float v1 = fmaxf(acc[i][1] + bias[o + 1], 0.f);
    float v2 = fmaxf(acc[i][2] + bias[o + 2], 0.f);
    float v3 = fmaxf(acc[i][3] + bias[o + 3], 0.f);
    uint2 pk;
    pk.x = (uint)f2bf(v0) | ((uint)f2bf(v1) << 16);
    pk.y = (uint)f2bf(v2) | ((uint)f2bf(v3) << 16);
    *(uint2*)(Cb + (size_t)gn * OUT + o) = pk;
  }
}

// ---------------- MFMA GEMM (K=128): KIND 0: bf16+bias (gh). KIND 4: heads mu/lv f32 ----------------
template<int OUT, int KIND>
__global__ __launch_bounds__(256) void gemm_mfma(
    const ushort* __restrict__ A, const ushort* __restrict__ W,
    const float* __restrict__ bias, float* __restrict__ Cf,
    ushort* __restrict__ Cb, const float* __restrict__ bias2,
    float* __restrict__ Cf2, int N)
{
  constexpr int K = 128;
  constexpr int NOT = OUT / 16;
  const int lane = threadIdx.x & 63;
  const int wave = threadIdx.x >> 6;
  const int r = lane & 15;
  const int kg = lane >> 4;
  const int row0 = (blockIdx.x * 8 + wave * 2) * 16;
  if (row0 >= N) return;

  int arow0 = row0 + r;          if (arow0 >= N) arow0 = N - 1;
  int arow1 = row0 + 16 + r;     if (arow1 >= N) arow1 = N - 1;
  const ushort* ap0 = A + (size_t)arow0 * K + kg * 8;
  const ushort* ap1 = A + (size_t)arow1 * K + kg * 8;
  const ushort* wp = W + (size_t)r * K + kg * 8;

  bf16x8_t af[2][4];
#pragma unroll
  for (int kt = 0; kt < 4; ++kt) {
    af[0][kt] = *(const bf16x8_t*)(ap0 + kt * 32);
    af[1][kt] = *(const bf16x8_t*)(ap1 + kt * 32);
  }
#pragma unroll
  for (int otp = 0; otp < NOT / 2; ++otp) {
    bf16x8_t w0[4], w1[4];
#pragma unroll
    for (int kt = 0; kt < 4; ++kt) {
      w0[kt] = *(const bf16x8_t*)(wp + (size_t)(2 * otp) * 16 * K + kt * 32);
      w1[kt] = *(const bf16x8_t*)(wp + (size_t)(2 * otp + 1) * 16 * K + kt * 32);
    }
    f32x4 acc[2][2] = {{{0.f,0.f,0.f,0.f},{0.f,0.f,0.f,0.f}},
                       {{0.f,0.f,0.f,0.f},{0.f,0.f,0.f,0.f}}};
#pragma unroll
    for (int kt = 0; kt < 4; ++kt) {
#pragma unroll
      for (int rt = 0; rt < 2; ++rt) {
        acc[rt][0] = __builtin_amdgcn_mfma_f32_16x16x32_bf16(af[rt][kt], w0[kt], acc[rt][0], 0, 0, 0);
        acc[rt][1] = __builtin_amdgcn_mfma_f32_16x16x32_bf16(af[rt][kt], w1[kt], acc[rt][1], 0, 0, 0);
      }
    }
#pragma unroll
    for (int rt = 0; rt < 2; ++rt) {
#pragma unroll
      for (int oi = 0; oi < 2; ++oi) {
        int o = (2 * otp + oi) * 16 + r;
#pragma unroll
        for (int reg = 0; reg < 4; ++reg) {
          int n = row0 + rt * 16 + kg * 4 + reg;
          if (n >= N) continue;
          float v = acc[rt][oi][reg];
          if constexpr (KIND == 0) {
            Cb[(size_t)n * OUT + o] = f2bf(v + bias[o]);
          } else {
            if (o < 128) Cf[(size_t)n * 128 + o] = v + bias[o];
            else Cf2[(size_t)n * 128 + (o - 128)] = v + bias2[o - 128];
          }
        }
      }
    }
  }
}

// ---------------- fused GRU GEMM: gi = S @ Wcomb^T (K=512) + gate epilogue ----------------
__global__ __launch_bounds__(256) void gru_gemm(
    const ushort* __restrict__ S, const ushort* __restrict__ Wc,
    const float* __restrict__ bias, const ushort* __restrict__ ghb,
    const ushort* __restrict__ x0b, ushort* __restrict__ m_out, int N)
{
  constexpr int K = 512;
  const int lane = threadIdx.x & 63;
  const int wave = threadIdx.x >> 6;
  const int r = lane & 15;
  const int kg = lane >> 4;
  const int row0 = (blockIdx.x * 8 + wave * 2) * 16;
  if (row0 >= N) return;

  int arow0 = row0 + r;          if (arow0 >= N) arow0 = N - 1;
  int arow1 = row0 + 16 + r;     if (arow1 >= N) arow1 = N - 1;
  const ushort* ap0 = S + (size_t)arow0 * K + kg * 8;
  const ushort* ap1 = S + (size_t)arow1 * K + kg * 8;
  const ushort* wp = Wc + (size_t)r * K + kg * 8;

#pragma unroll 1
  for (int jg = 0; jg < 8; ++jg) {
    const ushort* wr = wp + (size_t)(jg) * 16 * K;
    const ushort* wz = wp + (size_t)(8 + jg) * 16 * K;
    const ushort* wn = wp + (size_t)(16 + jg) * 16 * K;
    f32x4 ar[2] = {{0.f,0.f,0.f,0.f},{0.f,0.f,0.f,0.f}};
    f32x4 az[2] = {{0.f,0.f,0.f,0.f},{0.f,0.f,0.f,0.f}};
    f32x4 an[2] = {{0.f,0.f,0.f,0.f},{0.f,0.f,0.f,0.f}};
#pragma unroll 4
    for (int kt = 0; kt < 16; ++kt) {
      bf16x8_t a0 = *(const bf16x8_t*)(ap0 + kt * 32);
      bf16x8_t a1 = *(const bf16x8_t*)(ap1 + kt * 32);
      bf16x8_t v0 = *(const bf16x8_t*)(wr + kt * 32);
      bf16x8_t v1 = *(const bf16x8_t*)(wz + kt * 32);
      bf16x8_t v2 = *(const bf16x8_t*)(wn + kt * 32);
      ar[0] = __builtin_amdgcn_mfma_f32_16x16x32_bf16(a0, v0, ar[0], 0, 0, 0);
      ar[1] = __builtin_amdgcn_mfma_f32_16x16x32_bf16(a1, v0, ar[1], 0, 0, 0);
      az[0] = __builtin_amdgcn_mfma_f32_16x16x32_bf16(a0, v1, az[0], 0, 0, 0);
      az[1] = __builtin_amdgcn_mfma_f32_16x16x32_bf16(a1, v1, az[1], 0, 0, 0);
      an[0] = __builtin_amdgcn_mfma_f32_16x16x32_bf16(a0, v2, an[0], 0, 0, 0);
      an[1] = __builtin_amdgcn_mfma_f32_16x16x32_bf16(a1, v2, an[1], 0, 0, 0);
    }
    int j = jg * 16 + r;
    float br = bias[j], bz = bias[128 + j], bn = bias[256 + j];
#pragma unroll
    for (int rt = 0; rt < 2; ++rt) {
#pragma unroll
      for (int reg = 0; reg < 4; ++reg) {
        int n = row0 + rt * 16 + kg * 4 + reg;
        if (n >= N) continue;
        const ushort* ghp = ghb + (size_t)n * 384;
        float gir = ar[rt][reg] + br + bf2f(ghp[j]);
        float giz = az[rt][reg] + bz + bf2f(ghp[128 + j]);
        float ghn = bf2f(ghp[256 + j]);
        float rr = 1.f / (1.f + expf(-gir));
        float zz = 1.f / (1.f + expf(-giz));
        float nn = tanhf(an[rt][reg] + bn + rr * ghn);
        float x0v = bf2f(x0b[(size_t)n * 128 + j]);
        float h = (1.f - zz) * nn + zz * x0v;
        m_out[(size_t)n * 128 + j] = f2bf(fmaxf(h, 0.f));
      }
    }
  }
}

// ---------------- weight conversion: w_hh + heads -> bf16 ----------------
#define WOFF_WHH 0
#define WOFF_HEADS 49152
#define WTOT 81920

__global__ __launch_bounds__(256) void convert_weights(
    const float* __restrict__ w_hh, const float* __restrict__ mu_w,
    const float* __restrict__ lv_w, ushort* __restrict__ wsb)
{
  int i = blockIdx.x * 256 + threadIdx.x;
  if (i >= WTOT) return;
  float v;
  if (i < WOFF_HEADS) v = w_hh[i];
  else {
    int k = i - WOFF_HEADS;
    v = (k < 16384) ? mu_w[k] : lv_w[k - 16384];
  }
  wsb[i] = f2bf(v);
}

// Wcomb[s][o][t*128+j] = 2 * sum_i w_ih[o,i] * gnn_w[s,t,i,j]   (f32 math, bf16 out)
__global__ __launch_bounds__(256) void make_wcomb(
    const float* __restrict__ w_ih, const float* __restrict__ gnn_w,
    ushort* __restrict__ wc)
{
  int idx = blockIdx.x * 256 + threadIdx.x;
  if (idx >= STEPS * 384 * 512) return;
  int s = idx / (384 * 512);
  int rem = idx % (384 * 512);
  int o = rem >> 9;
  int col = rem & 511;
  int t = col >> 7, j = col & 127;
  const float* wi = w_ih + (size_t)o * 128;
  const float* g = gnn_w + ((size_t)(s * 4 + t) * 128) * 128 + j;
  float acc = 0.f;
#pragma unroll 8
  for (int i = 0; i < 128; ++i) acc += wi[i] * g[(size_t)i * 128];
  wc[idx] = f2bf(2.f * acc);
}

// ---------------- CSR build keyed by (dst*4 + type) ----------------
__global__ __launch_bounds__(256) void hist_key(
    const int* __restrict__ ei, const float* __restrict__ ea,
    int* __restrict__ counts, int* __restrict__ ekey)
{
  int e = blockIdx.x * 256 + threadIdx.x;
  if (e >= E_EDGES) return;
  const float* a = ea + (size_t)e * T_TYPES;
  float bv = a[0]; int bi = 0;
#pragma unroll
  for (int t = 1; t < T_TYPES; ++t) {
    float v = a[t];
    if (v > bv) { bv = v; bi = t; }
  }
  int key = ei[E_EDGES + e] * 4 + bi;
  ekey[e] = key;
  atomicAdd(&counts[key], 1);
}

__global__ __launch_bounds__(1024) void scan_block(
    const int* __restrict__ counts, int* __restrict__ excl,
    int* __restrict__ bsum, int n)
{
  __shared__ int ls[1024];
  const int tid = threadIdx.x;
  const int i = blockIdx.x * 1024 + tid;
  int v = (i < n) ? counts[i] : 0;
  ls[tid] = v;
  __syncthreads();
  for (int off = 1; off < 1024; off <<= 1) {
    int t = (tid >= off) ? ls[tid - off] : 0;
    __syncthreads();
    ls[tid] += t;
    __syncthreads();
  }
  if (i < n) excl[i] = ls[tid] - v;
  if (tid == 1023) bsum[blockIdx.x] = ls[1023];
}

__global__ __launch_bounds__(256) void scan_bsums(
    const int* __restrict__ bsum, int* __restrict__ boff, int nb)
{
  __shared__ int ls[256];
  const int tid = threadIdx.x;
  int v = (tid < nb) ? bsum[tid] : 0;
  ls[tid] = v;
  __syncthreads();
  for (int off = 1; off < 256; off <<= 1) {
    int t = (tid >= off) ? ls[tid - off] : 0;
    __syncthreads();
    ls[tid] += t;
    __syncthreads();
  }
  if (tid < nb) boff[tid] = ls[tid] - v;
}

__global__ __launch_bounds__(1024) void scan_final(
    const int* __restrict__ excl, const int* __restrict__ boff,
    int* __restrict__ offsets, int* __restrict__ cursor, int n)
{
  int i = blockIdx.x * 1024 + threadIdx.x;
  if (i == 0) { offsets[n] = E_EDGES; }
  if (i >= n) return;
  int o = excl[i] + boff[blockIdx.x];
  offsets[i] = o;
  cursor[i] = o;
}

__global__ __launch_bounds__(256) void fill_csr(
    const int* __restrict__ ei, const int* __restrict__ ekey,
    int* __restrict__ cursor, int* __restrict__ esrc)
{
  int e = blockIdx.x * 256 + threadIdx.x;
  if (e >= E_EDGES) return;
  int pos = atomicAdd(&cursor[ekey[e]], 1);
  esrc[pos] = ei[e];
}

// ---------------- gather S: S[d][t*128+c] = sum_{e in (d,t)} m[src_e][c]  (bf16) ----------------
__global__ __launch_bounds__(256) void gather_S(
    const ushort* __restrict__ m, const int* __restrict__ offs4,
    const int* __restrict__ esrc, ushort* __restrict__ S, int nNodes)
{
  const int wave = threadIdx.x >> 6, lane = threadIdx.x & 63;
  const int node = blockIdx.x * 4 + wave;
  if (node >= nNodes) return;
  const int ch = lane * 2;
  uint* sp = (uint*)(S + (size_t)node * 512 + ch);
#pragma unroll
  for (int t = 0; t < T_TYPES; ++t) {
    const int beg = offs4[node * 4 + t];
    const int end = offs4[node * 4 + t + 1];
    float ax = 0.f, ay = 0.f;
    int j = beg;
    for (; j + 3 < end; j += 4) {
      int s0 = esrc[j], s1 = esrc[j + 1], s2 = esrc[j + 2], s3 = esrc[j + 3];
      uint h0 = *(const uint*)(m + (size_t)s0 * 128 + ch);
      uint h1 = *(const uint*)(m + (size_t)s1 * 128 + ch);
      uint h2 = *(const uint*)(m + (size_t)s2 * 128 + ch);
      uint h3 = *(const uint*)(m + (size_t)s3 * 128 + ch);
      ax += bf2f((ushort)(h0 & 0xffff)) + bf2f((ushort)(h1 & 0xffff))
          + bf2f((ushort)(h2 & 0xffff)) + bf2f((ushort)(h3 & 0xffff));
      ay += bf2f((ushort)(h0 >> 16)) + bf2f((ushort)(h1 >> 16))
          + bf2f((ushort)(h2 >> 16)) + bf2f((ushort)(h3 >> 16));
    }
    for (; j < end; ++j) {
      uint h0 = *(const uint*)(m + (size_t)esrc[j] * 128 + ch);
      ax += bf2f((ushort)(h0 & 0xffff));
      ay += bf2f((ushort)(h0 >> 16));
    }
    sp[t * 64] = (uint)f2bf(ax) | ((uint)f2bf(ay) << 16);
  }
}

extern "C" void kernel_launch(void* const* d_in, const int* in_sizes, int n_in,
                              void* d_out, int out_size, void* d_ws, size_t ws_size,
                              hipStream_t stream) {
  const float* x     = (const float*)d_in[0];
  const int*   ei    = (const int*)d_in[1];
  const float* eattr = (const float*)d_in[2];
  const float* lin_w = (const float*)d_in[3];
  const float* lin_b = (const float*)d_in[4];
  const float* gnn_w = (const float*)d_in[5];
  const float* w_ih  = (const float*)d_in[6];
  const float* w_hh  = (const float*)d_in[7];
  const float* b_ih  = (const float*)d_in[8];
  const float* b_hh  = (const float*)d_in[9];
  const float* mu_w  = (const float*)d_in[10];
  const float* mu_b  = (const float*)d_in[11];
  const float* lv_w  = (const float*)d_in[12];
  const float* lv_b  = (const float*)d_in[13];

  char* ws = (char*)d_ws;
  size_t off = 0;
  ushort* x0b = (ushort*)(ws + off); off += (size_t)N_NODES * L * 2;        // 12.8MB
  ushort* ghb = (ushort*)(ws + off); off += (size_t)N_NODES * 3 * L * 2;    // 38.4MB
  ushort* m_b = (ushort*)(ws + off); off += (size_t)N_NODES * L * 2;        // 12.8MB
  ushort* S   = (ushort*)(ws + off); off += (size_t)N_NODES * 4 * L * 2;    // 51.2MB
  ushort* wsb = (ushort*)(ws + off); off += (size_t)WTOT * 2;
  ushort* wcomb = (ushort*)(ws + off); off += (size_t)STEPS * 384 * 512 * 2; // 1.18MB
  int* counts  = (int*)(ws + off); off += (NB4 + 1024) * 4;
  int* excl    = (int*)(ws + off); off += (NB4 + 1024) * 4;
  int* offs4   = (int*)(ws + off); off += (NB4 + 1024) * 4;
  int* cursor4 = (int*)(ws + off); off += (NB4 + 1024) * 4;
  int* bsum    = (int*)(ws + off); off += 256 * 4;
  int* boff    = (int*)(ws + off); off += 256 * 4;
  int* ekey    = (int*)(ws + off); off += (size_t)E_EDGES * 4;
  int* esrc    = (int*)(ws + off); off += (size_t)E_EDGES * 4;

  dim3 blk(256);
  const int GEMM_GRID = (N_NODES + 127) / 128;  // 391
  const int NSB = (NB4 + 1023) / 1024;          // 196

  convert_weights<<<(WTOT + 255) / 256, blk, 0, stream>>>(w_hh, mu_w, lv_w, wsb);
  make_wcomb<<<(STEPS * 384 * 512 + 255) / 256, blk, 0, stream>>>(w_ih, gnn_w, wcomb);

  // CSR keyed by (dst*4+type), constant across steps
  hipMemsetAsync(counts, 0, NB4 * sizeof(int), stream);
  hist_key<<<(E_EDGES + 255) / 256, blk, 0, stream>>>(ei, eattr, counts, ekey);
  scan_block<<<NSB, 1024, 0, stream>>>(counts, excl, bsum, NB4);
  scan_bsums<<<1, 256, 0, stream>>>(bsum, boff, NSB);
  scan_final<<<NSB, 1024, 0, stream>>>(excl, boff, offs4, cursor4, NB4);
  fill_csr<<<(E_EDGES + 255) / 256, blk, 0, stream>>>(ei, ekey, cursor4, esrc);

  // x0 = relu(x @ lin_w^T + lin_b) -> bf16
  dim3 g_x0((N_NODES + BN - 1) / BN, L / BO);
  matmul_x0<<<g_x0, blk, 0, stream>>>(x, lin_w, lin_b, x0b, N_NODES, IN_F, L);

  // gh = x0 @ w_hh^T + b_hh -> bf16
  gemm_mfma<384, 0><<<GEMM_GRID, blk, 0, stream>>>(
      x0b, wsb + WOFF_WHH, b_hh, nullptr, ghb, nullptr, nullptr, N_NODES);

  const ushort* mcur = x0b;
  for (int s = 0; s < STEPS; ++s) {
    gather_S<<<(N_NODES + 3) / 4, blk, 0, stream>>>(mcur, offs4, esrc, S, N_NODES);
    gru_gemm<<<GEMM_GRID, blk, 0, stream>>>(
        S, wcomb + (size_t)s * 384 * 512, b_ih, ghb, x0b, m_b, N_NODES);
    mcur = m_b;
  }

  float* mu = (float*)d_out;
  float* lv = (float*)d_out + (size_t)N_NODES * L;
  gemm_mfma<256, 4><<<GEMM_GRID, blk, 0, stream>>>(
      m_b, wsb + WOFF_HEADS, mu_b, mu, nullptr, lv_b, lv, N_NODES);
}

// Round 7
// 795.290 us; speedup vs baseline: 1.2051x; 1.2051x over previous
//
#include <hip/hip_runtime.h>
#include <hip/hip_bf16.h>
#include <cmath>

#define N_NODES 50000
#define IN_F 64
#define L 128
#define STEPS 3
#define T_TYPES 4
#define E_EDGES 800000
#define NB4 (N_NODES * 4)

typedef __attribute__((ext_vector_type(8))) __bf16 bf16x8_t;
typedef __attribute__((ext_vector_type(4))) float f32x4;

__device__ inline float bf2f(ushort u) {
  union { uint i; float f; } v; v.i = ((uint)u) << 16; return v.f;
}
__device__ inline ushort f2bf(float f) {
  union { float f; uint u; } v; v.f = f;
  uint u = v.u;
  u += 0x7fffu + ((u >> 16) & 1u);  // RNE
  return (ushort)(u >> 16);
}

// ---------------- fp32 tiled matmul for x0 (K=64), writes bf16 ----------------
#define BN 64
#define BO 64
#define BK 16
__global__ __launch_bounds__(256) void matmul_x0(
    const float* __restrict__ A, const float* __restrict__ W,
    const float* __restrict__ bias, ushort* __restrict__ Cb,
    int N, int K, int OUT)
{
  __shared__ float As[BN][BK + 1];
  __shared__ float Ws[BO][BK + 1];
  const int tid = threadIdx.x;
  const int n_base = blockIdx.x * BN;
  const int o_base = blockIdx.y * BO;
  const int tx = tid & 15, ty = tid >> 4;
  const int n0 = ty * 4, o0 = tx * 4;
  const int lr = tid >> 2, lc = (tid & 3) * 4;
  float acc[4][4] = {{0.f, 0.f, 0.f, 0.f}};
  for (int kc = 0; kc < K; kc += BK) {
    int gn = n_base + lr;
    float4 av = make_float4(0.f, 0.f, 0.f, 0.f);
    if (gn < N) av = *(const float4*)(A + (size_t)gn * K + kc + lc);
    As[lr][lc + 0] = av.x; As[lr][lc + 1] = av.y;
    As[lr][lc + 2] = av.z; As[lr][lc + 3] = av.w;
    float4 wv = *(const float4*)(W + (size_t)(o_base + lr) * K + kc + lc);
    Ws[lr][lc + 0] = wv.x; Ws[lr][lc + 1] = wv.y;
    Ws[lr][lc + 2] = wv.z; Ws[lr][lc + 3] = wv.w;
    __syncthreads();
#pragma unroll
    for (int kk = 0; kk < BK; ++kk) {
      float a[4], w[4];
#pragma unroll
      for (int i = 0; i < 4; ++i) a[i] = As[n0 + i][kk];
#pragma unroll
      for (int j = 0; j < 4; ++j) w[j] = Ws[o0 + j][kk];
#pragma unroll
      for (int i = 0; i < 4; ++i)
#pragma unroll
        for (int j = 0; j < 4; ++j) acc[i][j] += a[i] * w[j];
    }
    __syncthreads();
  }
#pragma unroll
  for (int i = 0; i < 4; ++i) {
    int gn = n_base + n0 + i;
    if (gn >= N) continue;
    int o = o_base + o0;
    float v0 = fmaxf(acc[i][0] + bias[o + 0], 0.f);
    float v1 = fmaxf(acc[i][1] + bias[o + 1], 0.f);
    float v2 = fmaxf(acc[i][2] + bias[o + 2], 0.f);
    float v3 = fmaxf(acc[i][3] + bias[o + 3], 0.f);
    uint2 pk;
    pk.x = (uint)f2bf(v0) | ((uint)f2bf(v1) << 16);
    pk.y = (uint)f2bf(v2) | ((uint)f2bf(v3) << 16);
    *(uint2*)(Cb + (size_t)gn * OUT + o) = pk;
  }
}

// ---------------- MFMA GEMM (K=128): KIND 0: bf16+bias (gh). KIND 4: heads mu/lv f32 ----------------
template<int OUT, int KIND>
__global__ __launch_bounds__(256) void gemm_mfma(
    const ushort* __restrict__ A, const ushort* __restrict__ W,
    const float* __restrict__ bias, float* __restrict__ Cf,
    ushort* __restrict__ Cb, const float* __restrict__ bias2,
    float* __restrict__ Cf2, int N)
{
  constexpr int K = 128;
  constexpr int NOT = OUT / 16;
  const int lane = threadIdx.x & 63;
  const int wave = threadIdx.x >> 6;
  const int r = lane & 15;
  const int kg = lane >> 4;
  const int row0 = (blockIdx.x * 8 + wave * 2) * 16;
  if (row0 >= N) return;

  int arow0 = row0 + r;          if (arow0 >= N) arow0 = N - 1;
  int arow1 = row0 + 16 + r;     if (arow1 >= N) arow1 = N - 1;
  const ushort* ap0 = A + (size_t)arow0 * K + kg * 8;
  const ushort* ap1 = A + (size_t)arow1 * K + kg * 8;
  const ushort* wp = W + (size_t)r * K + kg * 8;

  bf16x8_t af[2][4];
#pragma unroll
  for (int kt = 0; kt < 4; ++kt) {
    af[0][kt] = *(const bf16x8_t*)(ap0 + kt * 32);
    af[1][kt] = *(const bf16x8_t*)(ap1 + kt * 32);
  }
#pragma unroll
  for (int otp = 0; otp < NOT / 2; ++otp) {
    bf16x8_t w0[4], w1[4];
#pragma unroll
    for (int kt = 0; kt < 4; ++kt) {
      w0[kt] = *(const bf16x8_t*)(wp + (size_t)(2 * otp) * 16 * K + kt * 32);
      w1[kt] = *(const bf16x8_t*)(wp + (size_t)(2 * otp + 1) * 16 * K + kt * 32);
    }
    f32x4 acc[2][2] = {{{0.f,0.f,0.f,0.f},{0.f,0.f,0.f,0.f}},
                       {{0.f,0.f,0.f,0.f},{0.f,0.f,0.f,0.f}}};
#pragma unroll
    for (int kt = 0; kt < 4; ++kt) {
#pragma unroll
      for (int rt = 0; rt < 2; ++rt) {
        acc[rt][0] = __builtin_amdgcn_mfma_f32_16x16x32_bf16(af[rt][kt], w0[kt], acc[rt][0], 0, 0, 0);
        acc[rt][1] = __builtin_amdgcn_mfma_f32_16x16x32_bf16(af[rt][kt], w1[kt], acc[rt][1], 0, 0, 0);
      }
    }
#pragma unroll
    for (int rt = 0; rt < 2; ++rt) {
#pragma unroll
      for (int oi = 0; oi < 2; ++oi) {
        int o = (2 * otp + oi) * 16 + r;
#pragma unroll
        for (int reg = 0; reg < 4; ++reg) {
          int n = row0 + rt * 16 + kg * 4 + reg;
          if (n >= N) continue;
          float v = acc[rt][oi][reg];
          if constexpr (KIND == 0) {
            Cb[(size_t)n * OUT + o] = f2bf(v + bias[o]);
          } else {
            if (o < 128) Cf[(size_t)n * 128 + o] = v + bias[o];
            else Cf2[(size_t)n * 128 + (o - 128)] = v + bias2[o - 128];
          }
        }
      }
    }
  }
}

// ---------------- fused GRU GEMM: gi = S @ Wcomb^T (K=512), K-outer, LDS-staged W ----------------
// 256 thr = 4 waves = 2 row-groups (32 rows) x 2 out-halves (12 tiles).
// Wcomb rows pre-permuted: o' = jg*48 + gate*16 + rr  (triples contiguous).
__global__ __launch_bounds__(256, 2) void gru_gemm(
    const ushort* __restrict__ S, const ushort* __restrict__ Wc,
    const float* __restrict__ bias, const ushort* __restrict__ ghb,
    const ushort* __restrict__ x0b, ushort* __restrict__ m_out, int N)
{
  __shared__ ushort wlds[24576];  // 48KB: unit e=(o'*8+q), 16B each
  const int tid = threadIdx.x;
  const int lane = tid & 63;
  const int wave = tid >> 6;
  const int rg = wave & 1;        // row group
  const int oh = wave >> 1;       // out half
  const int r = lane & 15;
  const int kg = lane >> 4;
  const int row0 = blockIdx.x * 64 + rg * 32;

  int arow0 = row0 + r;       if (arow0 >= N) arow0 = N - 1;
  int arow1 = row0 + 16 + r;  if (arow1 >= N) arow1 = N - 1;
  const ushort* ap0 = S + (size_t)arow0 * 512 + kg * 8;
  const ushort* ap1 = S + (size_t)arow1 * 512 + kg * 8;

  f32x4 acc[2][12];
#pragma unroll
  for (int rt = 0; rt < 2; ++rt)
#pragma unroll
    for (int ot = 0; ot < 12; ++ot) acc[rt][ot] = {0.f, 0.f, 0.f, 0.f};

  for (int c = 0; c < 8; ++c) {
    __syncthreads();
    // stage 48KB chunk: W[o'][c*64 .. c*64+64) ushorts, 12 units of 16B per thread
#pragma unroll
    for (int i = 0; i < 12; ++i) {
      int e = i * 256 + tid;
      int o = e >> 3, q = e & 7;
      uint4 v = *(const uint4*)(Wc + (size_t)o * 512 + c * 64 + q * 8);
      *(uint4*)(wlds + (size_t)e * 8) = v;
    }
    __syncthreads();
#pragma unroll
    for (int kk = 0; kk < 2; ++kk) {
      bf16x8_t a0 = *(const bf16x8_t*)(ap0 + c * 64 + kk * 32);
      bf16x8_t a1 = *(const bf16x8_t*)(ap1 + c * 64 + kk * 32);
#pragma unroll
      for (int ot = 0; ot < 12; ++ot) {
        int gt = oh * 12 + ot;
        bf16x8_t w = *(const bf16x8_t*)(wlds + ((size_t)(gt * 16 + r) * 8 + kk * 4 + kg) * 8);
        acc[0][ot] = __builtin_amdgcn_mfma_f32_16x16x32_bf16(a0, w, acc[0][ot], 0, 0, 0);
        acc[1][ot] = __builtin_amdgcn_mfma_f32_16x16x32_bf16(a1, w, acc[1][ot], 0, 0, 0);
      }
    }
  }

  // epilogue: out-half oh owns jg = oh*4 .. oh*4+4, tiles (jl*3 + gate)
#pragma unroll
  for (int jl = 0; jl < 4; ++jl) {
    int jg = oh * 4 + jl;
    int j = jg * 16 + r;
    float br = bias[j], bz = bias[128 + j], bn = bias[256 + j];
#pragma unroll
    for (int rt = 0; rt < 2; ++rt) {
#pragma unroll
      for (int reg = 0; reg < 4; ++reg) {
        int n = row0 + rt * 16 + kg * 4 + reg;
        if (n >= N) continue;
        const ushort* ghp = ghb + (size_t)n * 384;
        float gir = acc[rt][jl * 3 + 0][reg] + br + bf2f(ghp[j]);
        float giz = acc[rt][jl * 3 + 1][reg] + bz + bf2f(ghp[128 + j]);
        float ghn = bf2f(ghp[256 + j]);
        float rr = 1.f / (1.f + expf(-gir));
        float zz = 1.f / (1.f + expf(-giz));
        float nn = tanhf(acc[rt][jl * 3 + 2][reg] + bn + rr * ghn);
        float x0v = bf2f(x0b[(size_t)n * 128 + j]);
        float h = (1.f - zz) * nn + zz * x0v;
        m_out[(size_t)n * 128 + j] = f2bf(fmaxf(h, 0.f));
      }
    }
  }
}

// ---------------- weight conversion: w_hh + heads -> bf16 ----------------
#define WOFF_WHH 0
#define WOFF_HEADS 49152
#define WTOT 81920

__global__ __launch_bounds__(256) void convert_weights(
    const float* __restrict__ w_hh, const float* __restrict__ mu_w,
    const float* __restrict__ lv_w, ushort* __restrict__ wsb)
{
  int i = blockIdx.x * 256 + threadIdx.x;
  if (i >= WTOT) return;
  float v;
  if (i < WOFF_HEADS) v = w_hh[i];
  else {
    int k = i - WOFF_HEADS;
    v = (k < 16384) ? mu_w[k] : lv_w[k - 16384];
  }
  wsb[i] = f2bf(v);
}

// Wcomb[s][o'][t*128+j] = 2 * sum_i w_ih[o,i] * gnn_w[s,t,i,j]
// row permutation: o' = jg*48 + g*16 + rr  <->  o = g*128 + jg*16 + rr
__global__ __launch_bounds__(256) void make_wcomb(
    const float* __restrict__ w_ih, const float* __restrict__ gnn_w,
    ushort* __restrict__ wc)
{
  int idx = blockIdx.x * 256 + threadIdx.x;
  if (idx >= STEPS * 384 * 512) return;
  int s = idx / (384 * 512);
  int rem = idx % (384 * 512);
  int op = rem >> 9;
  int col = rem & 511;
  int jg = op / 48;
  int rem2 = op % 48;
  int g = rem2 / 16;
  int rr = rem2 % 16;
  int o = g * 128 + jg * 16 + rr;
  int t = col >> 7, jj = col & 127;
  const float* wi = w_ih + (size_t)o * 128;
  const float* gp = gnn_w + ((size_t)(s * 4 + t) * 128) * 128 + jj;
  float acc = 0.f;
#pragma unroll 8
  for (int i = 0; i < 128; ++i) acc += wi[i] * gp[(size_t)i * 128];
  wc[idx] = f2bf(2.f * acc);
}

// ---------------- CSR build keyed by (dst*4 + type) ----------------
__global__ __launch_bounds__(256) void hist_key(
    const int* __restrict__ ei, const float* __restrict__ ea,
    int* __restrict__ counts, int* __restrict__ ekey)
{
  int e = blockIdx.x * 256 + threadIdx.x;
  if (e >= E_EDGES) return;
  const float* a = ea + (size_t)e * T_TYPES;
  float bv = a[0]; int bi = 0;
#pragma unroll
  for (int t = 1; t < T_TYPES; ++t) {
    float v = a[t];
    if (v > bv) { bv = v; bi = t; }
  }
  int key = ei[E_EDGES + e] * 4 + bi;
  ekey[e] = key;
  atomicAdd(&counts[key], 1);
}

__global__ __launch_bounds__(1024) void scan_block(
    const int* __restrict__ counts, int* __restrict__ excl,
    int* __restrict__ bsum, int n)
{
  __shared__ int ls[1024];
  const int tid = threadIdx.x;
  const int i = blockIdx.x * 1024 + tid;
  int v = (i < n) ? counts[i] : 0;
  ls[tid] = v;
  __syncthreads();
  for (int off = 1; off < 1024; off <<= 1) {
    int t = (tid >= off) ? ls[tid - off] : 0;
    __syncthreads();
    ls[tid] += t;
    __syncthreads();
  }
  if (i < n) excl[i] = ls[tid] - v;
  if (tid == 1023) bsum[blockIdx.x] = ls[1023];
}

__global__ __launch_bounds__(256) void scan_bsums(
    const int* __restrict__ bsum, int* __restrict__ boff, int nb)
{
  __shared__ int ls[256];
  const int tid = threadIdx.x;
  int v = (tid < nb) ? bsum[tid] : 0;
  ls[tid] = v;
  __syncthreads();
  for (int off = 1; off < 256; off <<= 1) {
    int t = (tid >= off) ? ls[tid - off] : 0;
    __syncthreads();
    ls[tid] += t;
    __syncthreads();
  }
  if (tid < nb) boff[tid] = ls[tid] - v;
}

__global__ __launch_bounds__(1024) void scan_final(
    const int* __restrict__ excl, const int* __restrict__ boff,
    int* __restrict__ offsets, int* __restrict__ cursor, int n)
{
  int i = blockIdx.x * 1024 + threadIdx.x;
  if (i == 0) { offsets[n] = E_EDGES; }
  if (i >= n) return;
  int o = excl[i] + boff[blockIdx.x];
  offsets[i] = o;
  cursor[i] = o;
}

__global__ __launch_bounds__(256) void fill_csr(
    const int* __restrict__ ei, const int* __restrict__ ekey,
    int* __restrict__ cursor, int* __restrict__ esrc)
{
  int e = blockIdx.x * 256 + threadIdx.x;
  if (e >= E_EDGES) return;
  int pos = atomicAdd(&cursor[ekey[e]], 1);
  esrc[pos] = ei[e];
}

// ---------------- gather S: S[d][t*128+c] = sum_{e in (d,t)} m[src_e][c]  (bf16) ----------------
__global__ __launch_bounds__(256) void gather_S(
    const ushort* __restrict__ m, const int* __restrict__ offs4,
    const int* __restrict__ esrc, ushort* __restrict__ S, int nNodes)
{
  const int wave = threadIdx.x >> 6, lane = threadIdx.x & 63;
  const int node = blockIdx.x * 4 + wave;
  if (node >= nNodes) return;
  const int ch = lane * 2;
  uint* sp = (uint*)(S + (size_t)node * 512 + ch);
#pragma unroll
  for (int t = 0; t < T_TYPES; ++t) {
    const int beg = offs4[node * 4 + t];
    const int end = offs4[node * 4 + t + 1];
    float ax = 0.f, ay = 0.f;
    int j = beg;
    for (; j + 3 < end; j += 4) {
      int s0 = esrc[j], s1 = esrc[j + 1], s2 = esrc[j + 2], s3 = esrc[j + 3];
      uint h0 = *(const uint*)(m + (size_t)s0 * 128 + ch);
      uint h1 = *(const uint*)(m + (size_t)s1 * 128 + ch);
      uint h2 = *(const uint*)(m + (size_t)s2 * 128 + ch);
      uint h3 = *(const uint*)(m + (size_t)s3 * 128 + ch);
      ax += bf2f((ushort)(h0 & 0xffff)) + bf2f((ushort)(h1 & 0xffff))
          + bf2f((ushort)(h2 & 0xffff)) + bf2f((ushort)(h3 & 0xffff));
      ay += bf2f((ushort)(h0 >> 16)) + bf2f((ushort)(h1 >> 16))
          + bf2f((ushort)(h2 >> 16)) + bf2f((ushort)(h3 >> 16));
    }
    for (; j < end; ++j) {
      uint h0 = *(const uint*)(m + (size_t)esrc[j] * 128 + ch);
      ax += bf2f((ushort)(h0 & 0xffff));
      ay += bf2f((ushort)(h0 >> 16));
    }
    sp[t * 64] = (uint)f2bf(ax) | ((uint)f2bf(ay) << 16);
  }
}

extern "C" void kernel_launch(void* const* d_in, const int* in_sizes, int n_in,
                              void* d_out, int out_size, void* d_ws, size_t ws_size,
                              hipStream_t stream) {
  const float* x     = (const float*)d_in[0];
  const int*   ei    = (const int*)d_in[1];
  const float* eattr = (const float*)d_in[2];
  const float* lin_w = (const float*)d_in[3];
  const float* lin_b = (const float*)d_in[4];
  const float* gnn_w = (const float*)d_in[5];
  const float* w_ih  = (const float*)d_in[6];
  const float* w_hh  = (const float*)d_in[7];
  const float* b_ih  = (const float*)d_in[8];
  const float* b_hh  = (const float*)d_in[9];
  const float* mu_w  = (const float*)d_in[10];
  const float* mu_b  = (const float*)d_in[11];
  const float* lv_w  = (const float*)d_in[12];
  const float* lv_b  = (const float*)d_in[13];

  char* ws = (char*)d_ws;
  size_t off = 0;
  ushort* x0b = (ushort*)(ws + off); off += (size_t)N_NODES * L * 2;        // 12.8MB
  ushort* ghb = (ushort*)(ws + off); off += (size_t)N_NODES * 3 * L * 2;    // 38.4MB
  ushort* m_b = (ushort*)(ws + off); off += (size_t)N_NODES * L * 2;        // 12.8MB
  ushort* S   = (ushort*)(ws + off); off += (size_t)N_NODES * 4 * L * 2;    // 51.2MB
  ushort* wsb = (ushort*)(ws + off); off += (size_t)WTOT * 2;
  ushort* wcomb = (ushort*)(ws + off); off += (size_t)STEPS * 384 * 512 * 2; // 1.18MB
  int* counts  = (int*)(ws + off); off += (NB4 + 1024) * 4;
  int* excl    = (int*)(ws + off); off += (NB4 + 1024) * 4;
  int* offs4   = (int*)(ws + off); off += (NB4 + 1024) * 4;
  int* cursor4 = (int*)(ws + off); off += (NB4 + 1024) * 4;
  int* bsum    = (int*)(ws + off); off += 256 * 4;
  int* boff    = (int*)(ws + off); off += 256 * 4;
  int* ekey    = (int*)(ws + off); off += (size_t)E_EDGES * 4;
  int* esrc    = (int*)(ws + off); off += (size_t)E_EDGES * 4;

  dim3 blk(256);
  const int GEMM_GRID = (N_NODES + 127) / 128;   // 391  (K=128 gemms)
  const int GRU_GRID  = (N_NODES + 63) / 64;     // 782  (64 rows/block)
  const int NSB = (NB4 + 1023) / 1024;           // 196

  convert_weights<<<(WTOT + 255) / 256, blk, 0, stream>>>(w_hh, mu_w, lv_w, wsb);
  make_wcomb<<<(STEPS * 384 * 512 + 255) / 256, blk, 0, stream>>>(w_ih, gnn_w, wcomb);

  // CSR keyed by (dst*4+type), constant across steps
  hipMemsetAsync(counts, 0, NB4 * sizeof(int), stream);
  hist_key<<<(E_EDGES + 255) / 256, blk, 0, stream>>>(ei, eattr, counts, ekey);
  scan_block<<<NSB, 1024, 0, stream>>>(counts, excl, bsum, NB4);
  scan_bsums<<<1, 256, 0, stream>>>(bsum, boff, NSB);
  scan_final<<<NSB, 1024, 0, stream>>>(excl, boff, offs4, cursor4, NB4);
  fill_csr<<<(E_EDGES + 255) / 256, blk, 0, stream>>>(ei, ekey, cursor4, esrc);

  // x0 = relu(x @ lin_w^T + lin_b) -> bf16
  dim3 g_x0((N_NODES + BN - 1) / BN, L / BO);
  matmul_x0<<<g_x0, blk, 0, stream>>>(x, lin_w, lin_b, x0b, N_NODES, IN_F, L);

  // gh = x0 @ w_hh^T + b_hh -> bf16
  gemm_mfma<384, 0><<<GEMM_GRID, blk, 0, stream>>>(
      x0b, wsb + WOFF_WHH, b_hh, nullptr, ghb, nullptr, nullptr, N_NODES);

  const ushort* mcur = x0b;
  for (int s = 0; s < STEPS; ++s) {
    gather_S<<<(N_NODES + 3) / 4, blk, 0, stream>>>(mcur, offs4, esrc, S, N_NODES);
    gru_gemm<<<GRU_GRID, blk, 0, stream>>>(
        S, wcomb + (size_t)s * 384 * 512, b_ih, ghb, x0b, m_b, N_NODES);
    mcur = m_b;
  }

  float* mu = (float*)d_out;
  float* lv = (float*)d_out + (size_t)N_NODES * L;
  gemm_mfma<256, 4><<<GEMM_GRID, blk, 0, stream>>>(
      m_b, wsb + WOFF_HEADS, mu_b, mu, nullptr, lv_b, lv, N_NODES);
}